// Round 1
// baseline (82.668 us; speedup 1.0000x reference)
//
#include <hip/hip_runtime.h>
#include <hip/hip_bf16.h>
#include <math.h>

// ---- problem constants ----
#define SS 2304       // S = B*C*K*K = 4*64*9
#define LW 9          // L = HO*WO
#define EE 12
#define NHEAD 4
#define DHEAD 3
#define FFD 24

#if defined(__has_builtin)
#if __has_builtin(__builtin_amdgcn_exp2f)
#define EXP2(x) __builtin_amdgcn_exp2f(x)
#endif
#endif
#ifndef EXP2
#define EXP2(x) exp2f(x)
#endif

// ============================================================
// K1: seq = ce[c] + pe[n] + x[b,c,pi+hi,pj+wj];  qkv = seq @ W^T + b
// one thread per (s, n); 20736 threads = 81 blocks x 256
// ============================================================
__global__ __launch_bounds__(256) void k1_embed_qkv(
    const float* __restrict__ x, const float* __restrict__ ce,
    const float* __restrict__ pe, const float* __restrict__ w,
    const float* __restrict__ bias, float* __restrict__ qkv) {
  __shared__ float lw[432];
  __shared__ float lb[36];
  const int tid = threadIdx.x;
  for (int i = tid; i < 432; i += 256) lw[i] = w[i];
  if (tid < 36) lb[tid] = bias[tid];
  __syncthreads();

  const int idx = blockIdx.x * 256 + tid;  // = s*9 + n
  const int n = idx % 9;
  const int s = idx / 9;
  const int p = s % 9;
  const int c = (s / 9) % 64;
  const int b = s / 576;
  const int pi = p / 3, pj = p % 3;
  const int hi = n / 3, wj = n % 3;
  const float val = x[((b * 64 + c) * 5 + (pi + hi)) * 5 + (pj + wj)];

  float sq[12];
#pragma unroll
  for (int e = 0; e < 12; ++e) sq[e] = ce[c * 12 + e] + pe[n * 12 + e] + val;

  float* qo = qkv + (size_t)idx * 36;
#pragma unroll
  for (int r = 0; r < 36; ++r) {
    float acc = lb[r];
#pragma unroll
    for (int e = 0; e < 12; ++e) acc = fmaf(lw[r * 12 + e], sq[e], acc);
    qo[r] = acc;
  }
}

// ============================================================
// K2: flash attention partials. One block = (n,h, s-chunk of 256, t-chunk).
// K/V for the t-chunk staged in LDS (stages of 576 t).
// Unnormalized: part = (sum_exp, sum_exp*v0..v2); no max needed (|score|<~6).
// ============================================================
__global__ __launch_bounds__(256) void k2_attn(
    const float* __restrict__ qkv, float4* __restrict__ part, int tsplit) {
  __shared__ float kv[576 * 6];
  const int tid = threadIdx.x;
  const int bid = blockIdx.x;
  const int tc = bid % tsplit;
  const int tmp = bid / tsplit;
  const int scnk = tmp % 9;
  const int nh = tmp / 9;  // n*4 + h
  const int n = nh >> 2, h = nh & 3;
  const int tchunk = SS / tsplit;

  const int s = scnk * 256 + tid;
  const float* qp = qkv + ((size_t)s * 9 + n) * 36 + h * 3;
  const float QSC = 0.8329506128860126f;  // log2(e)/sqrt(3)
  const float q0 = qp[0] * QSC, q1 = qp[1] * QSC, q2 = qp[2] * QSC;

  float l = 0.f, a0 = 0.f, a1 = 0.f, a2 = 0.f;
  const int t0beg = tc * tchunk, t0end = t0beg + tchunk;
  for (int t0 = t0beg; t0 < t0end; t0 += 576) {
    __syncthreads();
    for (int tt = tid; tt < 576; tt += 256) {
      const float* kp = qkv + ((size_t)(t0 + tt) * 9 + n) * 36 + 12 + h * 3;
      kv[tt * 6 + 0] = kp[0];
      kv[tt * 6 + 1] = kp[1];
      kv[tt * 6 + 2] = kp[2];
      kv[tt * 6 + 3] = kp[12];   // v0 (v starts 12 floats after k)
      kv[tt * 6 + 4] = kp[13];
      kv[tt * 6 + 5] = kp[14];
    }
    __syncthreads();
    const float2* kv2 = (const float2*)kv;
#pragma unroll 8
    for (int tt = 0; tt < 576; ++tt) {
      const float2 ka = kv2[tt * 3 + 0];  // k0,k1
      const float2 kb = kv2[tt * 3 + 1];  // k2,v0
      const float2 kc = kv2[tt * 3 + 2];  // v1,v2
      const float sc = fmaf(q0, ka.x, fmaf(q1, ka.y, q2 * kb.x));
      const float pexp = EXP2(sc);
      l += pexp;
      a0 = fmaf(pexp, kb.y, a0);
      a1 = fmaf(pexp, kc.x, a1);
      a2 = fmaf(pexp, kc.y, a2);
    }
  }
  part[((size_t)nh * SS + s) * tsplit + tc] = make_float4(l, a0, a1, a2);
}

// ============================================================
// K3: combine partials -> ctx; out_proj; +seq residual; LN1; FF; LN2; linear.
// One thread per (s,n). seq recomputed on the fly (cheap).
// ============================================================
__global__ __launch_bounds__(256) void k3_mlp(
    const float4* __restrict__ part, const float* __restrict__ x,
    const float* __restrict__ ce, const float* __restrict__ pe,
    const float* __restrict__ opw, const float* __restrict__ opb,
    const float* __restrict__ ln1w, const float* __restrict__ ln1b,
    const float* __restrict__ f1w, const float* __restrict__ f1b,
    const float* __restrict__ f2w, const float* __restrict__ f2b,
    const float* __restrict__ ln2w, const float* __restrict__ ln2b,
    const float* __restrict__ linw, const float* __restrict__ linb,
    float* __restrict__ proj, int tsplit) {
  // LDS weight cache: opw 0..144 | opb 144 | ln1w 156 | ln1b 168 | f1w 180
  //                   f1b 468 | f2w 492 | f2b 780 | ln2w 792 | ln2b 804 | linw 816
  __shared__ float L[828];
  const int tid = threadIdx.x;
  for (int i = tid; i < 144; i += 256) L[i] = opw[i];
  for (int i = tid; i < 288; i += 256) {
    L[180 + i] = f1w[i];
    L[492 + i] = f2w[i];
  }
  if (tid < 12) {
    L[144 + tid] = opb[tid];
    L[156 + tid] = ln1w[tid];
    L[168 + tid] = ln1b[tid];
    L[780 + tid] = f2b[tid];
    L[792 + tid] = ln2w[tid];
    L[804 + tid] = ln2b[tid];
    L[816 + tid] = linw[tid];
  }
  if (tid < 24) L[468 + tid] = f1b[tid];
  __syncthreads();

  const int idx = blockIdx.x * 256 + tid;  // s*9 + n
  const int n = idx % 9;
  const int s = idx / 9;
  const int p = s % 9;
  const int c = (s / 9) % 64;
  const int b = s / 576;
  const int pi = p / 3, pj = p % 3;
  const int hi = n / 3, wj = n % 3;
  const float val = x[((b * 64 + c) * 5 + (pi + hi)) * 5 + (pj + wj)];

  // combine attention partials
  float ctx[12];
#pragma unroll
  for (int h = 0; h < 4; ++h) {
    float l = 0.f, b0 = 0.f, b1 = 0.f, b2 = 0.f;
    const float4* pp = part + ((size_t)(n * 4 + h) * SS + s) * tsplit;
    for (int t = 0; t < tsplit; ++t) {
      const float4 v = pp[t];
      l += v.x; b0 += v.y; b1 += v.z; b2 += v.w;
    }
    const float rl = 1.0f / l;
    ctx[h * 3 + 0] = b0 * rl;
    ctx[h * 3 + 1] = b1 * rl;
    ctx[h * 3 + 2] = b2 * rl;
  }

  // attn_out = opw @ ctx + opb;  x1 = seq + attn_out
  float x1[12];
#pragma unroll
  for (int e = 0; e < 12; ++e) {
    float acc = L[144 + e];
#pragma unroll
    for (int j = 0; j < 12; ++j) acc = fmaf(L[e * 12 + j], ctx[j], acc);
    const float seq_e = ce[c * 12 + e] + pe[n * 12 + e] + val;
    x1[e] = seq_e + acc;
  }

  // LN1
  float mu = 0.f;
#pragma unroll
  for (int e = 0; e < 12; ++e) mu += x1[e];
  mu *= (1.0f / 12.0f);
  float var = 0.f;
#pragma unroll
  for (int e = 0; e < 12; ++e) { const float d = x1[e] - mu; var = fmaf(d, d, var); }
  var *= (1.0f / 12.0f);
  float rs = rsqrtf(var + 1e-5f);
  float h1[12];
#pragma unroll
  for (int e = 0; e < 12; ++e) h1[e] = (x1[e] - mu) * rs * L[156 + e] + L[168 + e];

  // FF: relu(h1 @ f1w^T + f1b) @ f2w^T + f2b
  float f[24];
#pragma unroll
  for (int r = 0; r < 24; ++r) {
    float acc = L[468 + r];
#pragma unroll
    for (int e = 0; e < 12; ++e) acc = fmaf(L[180 + r * 12 + e], h1[e], acc);
    f[r] = fmaxf(acc, 0.f);
  }
  float x2[12];
#pragma unroll
  for (int e = 0; e < 12; ++e) {
    float acc = L[780 + e];
#pragma unroll
    for (int r = 0; r < 24; ++r) acc = fmaf(L[492 + e * 24 + r], f[r], acc);
    x2[e] = h1[e] + acc;
  }

  // LN2
  mu = 0.f;
#pragma unroll
  for (int e = 0; e < 12; ++e) mu += x2[e];
  mu *= (1.0f / 12.0f);
  var = 0.f;
#pragma unroll
  for (int e = 0; e < 12; ++e) { const float d = x2[e] - mu; var = fmaf(d, d, var); }
  var *= (1.0f / 12.0f);
  rs = rsqrtf(var + 1e-5f);

  // final linear
  float pv = linb[0];
#pragma unroll
  for (int e = 0; e < 12; ++e) {
    const float h2 = (x2[e] - mu) * rs * L[792 + e] + L[804 + e];
    pv = fmaf(L[816 + e], h2, pv);
  }
  proj[idx] = pv;
}

// ============================================================
// K4: fold (overlap-add). One thread per output pixel (6400 = 25x256).
// ============================================================
__global__ __launch_bounds__(256) void k4_fold(const float* __restrict__ proj,
                                               float* __restrict__ out) {
  const int o = blockIdx.x * 256 + threadIdx.x;
  const int ww = o % 5;
  const int hh = (o / 5) % 5;
  const int c = (o / 25) % 64;
  const int b = o / 1600;
  float sum = 0.f;
#pragma unroll
  for (int i = 0; i < 3; ++i) {
    const int hi = hh - i;
    if (hi < 0 || hi > 2) continue;
#pragma unroll
    for (int j = 0; j < 3; ++j) {
      const int wj = ww - j;
      if (wj < 0 || wj > 2) continue;
      sum += proj[(size_t)(b * 576 + c * 9 + i * 3 + j) * 9 + hi * 3 + wj];
    }
  }
  out[o] = sum;
}

extern "C" void kernel_launch(void* const* d_in, const int* in_sizes, int n_in,
                              void* d_out, int out_size, void* d_ws, size_t ws_size,
                              hipStream_t stream) {
  const float* x    = (const float*)d_in[0];
  const float* ce   = (const float*)d_in[1];
  const float* pe   = (const float*)d_in[2];
  const float* ipw  = (const float*)d_in[3];
  const float* ipb  = (const float*)d_in[4];
  const float* opw  = (const float*)d_in[5];
  const float* opb  = (const float*)d_in[6];
  const float* ln1w = (const float*)d_in[7];
  const float* ln1b = (const float*)d_in[8];
  const float* f1w  = (const float*)d_in[9];
  const float* f1b  = (const float*)d_in[10];
  const float* f2w  = (const float*)d_in[11];
  const float* f2b  = (const float*)d_in[12];
  const float* ln2w = (const float*)d_in[13];
  const float* ln2b = (const float*)d_in[14];
  const float* linw = (const float*)d_in[15];
  const float* linb = (const float*)d_in[16];

  float* wsf = (float*)d_ws;
  const size_t wsn = ws_size / sizeof(float);

  // ws layout (floats): qkv [0, 746496) | part float4 [746496, +36*SS*tsplit*4) | proj
  int tsplit = 4;  // degrade if workspace is small
  while (tsplit > 1 &&
         (746496u + 20736u + (size_t)36 * SS * 4 * tsplit) > wsn)
    tsplit >>= 1;

  float* qkv  = wsf;
  float4* part = (float4*)(wsf + 746496);  // byte offset 2985984, 16B-aligned
  float* proj = wsf + 746496 + (size_t)36 * SS * 4 * tsplit;

  k1_embed_qkv<<<81, 256, 0, stream>>>(x, ce, pe, ipw, ipb, qkv);
  k2_attn<<<36 * 9 * tsplit, 256, 0, stream>>>(qkv, part, tsplit);
  k3_mlp<<<81, 256, 0, stream>>>(part, x, ce, pe, opw, opb, ln1w, ln1b, f1w,
                                 f1b, f2w, f2b, ln2w, ln2b, linw, linb, proj,
                                 tsplit);
  k4_fold<<<25, 256, 0, stream>>>(proj, (float*)d_out);
}

// Round 2
// 54.902 us; speedup vs baseline: 1.5057x; 1.5057x over previous
//
#include <hip/hip_runtime.h>
#include <hip/hip_bf16.h>
#include <math.h>

// ---- problem constants ----
#define SS 2304       // S = B*C*K*K
#define QSCALE 0.8329506128860126f  // log2(e)/sqrt(3)

#if defined(__has_builtin)
#if __has_builtin(__builtin_amdgcn_exp2f)
#define EXP2(x) __builtin_amdgcn_exp2f(x)
#endif
#endif
#ifndef EXP2
#define EXP2(x) exp2f(x)
#endif

typedef short s8v __attribute__((ext_vector_type(8)));
typedef float f32x16 __attribute__((ext_vector_type(16)));

static __device__ __forceinline__ unsigned short f2b(float f) {
  __hip_bfloat16 h = __float2bfloat16(f);
  return __builtin_bit_cast(unsigned short, h);
}

// ============================================================
// K1: seq = ce[c]+pe[n]+x_val; qkv = W seq + b; emit bf16 Q,K,V^T
// per-head layouts for K2's MFMA:
//   Qb[nh][s][4] bf16 (q0*QSC,q1*QSC,q2*QSC,0)
//   Kb[nh][t][4] bf16 (k0,k1,k2,0)
//   Vt[nh][4][t] bf16 rows: v0,v1,v2,ones
// thread idx = n*2304 + s  (coalesced stores)
// ============================================================
__global__ __launch_bounds__(256) void k1_embed_qkv(
    const float* __restrict__ x, const float* __restrict__ ce,
    const float* __restrict__ pe, const float* __restrict__ w,
    const float* __restrict__ bias, unsigned short* __restrict__ Qb,
    unsigned short* __restrict__ Kb, unsigned short* __restrict__ Vt) {
  __shared__ float lw[432];
  __shared__ float lb[36];
  const int tid = threadIdx.x;
  for (int i = tid; i < 432; i += 256) lw[i] = w[i];
  if (tid < 36) lb[tid] = bias[tid];
  __syncthreads();

  const int idx = blockIdx.x * 256 + tid;  // n*2304 + s
  const int n = idx / 2304;
  const int s = idx % 2304;
  const int p = s % 9;
  const int c = (s / 9) % 64;
  const int b = s / 576;
  const int pi = p / 3, pj = p % 3;
  const int hi = n / 3, wj = n % 3;
  const float val = x[((b * 64 + c) * 5 + (pi + hi)) * 5 + (pj + wj)];

  float sq[12];
#pragma unroll
  for (int e = 0; e < 12; ++e) sq[e] = ce[c * 12 + e] + pe[n * 12 + e] + val;

  float out[36];
#pragma unroll
  for (int r = 0; r < 36; ++r) {
    float acc = lb[r];
#pragma unroll
    for (int e = 0; e < 12; ++e) acc = fmaf(lw[r * 12 + e], sq[e], acc);
    out[r] = acc;
  }

#pragma unroll
  for (int h = 0; h < 4; ++h) {
    const int nh = n * 4 + h;
    ushort4 qq;
    qq.x = f2b(out[h * 3 + 0] * QSCALE);
    qq.y = f2b(out[h * 3 + 1] * QSCALE);
    qq.z = f2b(out[h * 3 + 2] * QSCALE);
    qq.w = 0;
    *(ushort4*)(Qb + ((size_t)nh * SS + s) * 4) = qq;
    ushort4 kk;
    kk.x = f2b(out[12 + h * 3 + 0]);
    kk.y = f2b(out[12 + h * 3 + 1]);
    kk.z = f2b(out[12 + h * 3 + 2]);
    kk.w = 0;
    *(ushort4*)(Kb + ((size_t)nh * SS + s) * 4) = kk;
    const size_t vb = (size_t)(nh * 4) * SS + s;
    Vt[vb + 0 * SS] = f2b(out[24 + h * 3 + 0]);
    Vt[vb + 1 * SS] = f2b(out[24 + h * 3 + 1]);
    Vt[vb + 2 * SS] = f2b(out[24 + h * 3 + 2]);
    Vt[vb + 3 * SS] = 0x3F80;  // 1.0 bf16 (ones row -> sum_exp in acc[3])
  }
}

// ============================================================
// K2: MFMA flash attention (unnormalized, no running max needed).
// Swapped orientation: S^T = mfma(A=K_tile, B=Q_tile)  (32x32, K=16, dh=3 used)
//   -> exp2 -> cvt_pk_bf16 + permlane32_swap -> P^T B-frags
//   -> O^T += mfma(A=V^T frag, B=P^T)  twice (t=0..15, 16..31)
// Block = one nh x 128 s-rows (4 waves x 32). K/V^T staged in LDS.
// LDS map (ushort idx): K [0,9216) tokens x 4 | V^T rows at 9216 + d*2312
//   | 64B zero pad at 18464 (serves all unused-lane reads via broadcast)
// ============================================================
__global__ __launch_bounds__(256) void k2_attn(
    const unsigned short* __restrict__ Qb, const unsigned short* __restrict__ Kb,
    const unsigned short* __restrict__ Vt, float4* __restrict__ ctxb) {
  __shared__ unsigned short lds[18496];
  const int tid = threadIdx.x;
  const int nh = blockIdx.x / 18;
  const int schunk = blockIdx.x % 18;

  {
    const uint4* sk = (const uint4*)(Kb + (size_t)nh * (SS * 4));
    uint4* dk = (uint4*)lds;
    for (int i = tid; i < 1152; i += 256) dk[i] = sk[i];
    const uint4* sv = (const uint4*)(Vt + (size_t)nh * (4 * SS));
    for (int i = tid; i < 1152; i += 256) {
      const int r = i / 288, cc = i - r * 288;
      *(uint4*)(lds + 9216 + r * 2312 + cc * 8) = sv[i];
    }
    if (tid < 4) *(uint4*)(lds + 18464 + tid * 8) = make_uint4(0, 0, 0, 0);
  }
  __syncthreads();

  const int lane = tid & 63;
  const int wv = tid >> 6;
  const int h = lane >> 5;    // lane half
  const int sl = lane & 31;
  const int s0 = (schunk * 4 + wv) * 32;

  union F { s8v v; unsigned int u[4]; };

  // Q B-frag: B[k=(h*8+j)][col=sl] -> h==0 words (q0,q1),(q2,0); h==1 zero
  F fq;
  {
    const uint2 qw = *(const uint2*)(Qb + ((size_t)nh * SS + s0 + sl) * 4);
    fq.u[0] = h ? 0u : qw.x;
    fq.u[1] = h ? 0u : qw.y;
    fq.u[2] = 0u;
    fq.u[3] = 0u;
  }

  // per-tile LDS cursors (ushort indices); unused lanes park on the zero pad
  int koff = h ? 18464 : sl * 4;
  const int kinc = h ? 0 : 128;           // 32 tokens * 4 ushorts
  int voff = (sl < 4) ? (9216 + sl * 2312 + h * 8) : 18464;
  const int vinc = (sl < 4) ? 32 : 0;     // 32 t per tile

  f32x16 acc = {};
#pragma unroll 2
  for (int t = 0; t < 72; ++t) {
    // A-frag = K tile: A[row=t0+sl][k=h*8+j]; h==0 j0..2 = k0,k1,k2
    F fa;
    const uint2 kw = *(const uint2*)(lds + koff);
    fa.u[0] = kw.x; fa.u[1] = kw.y; fa.u[2] = 0u; fa.u[3] = 0u;
    f32x16 z = {};
    f32x16 sT = __builtin_amdgcn_mfma_f32_32x32x16_bf16(fa.v, fq.v, z, 0, 0, 0);

    float p[16];
#pragma unroll
    for (int r = 0; r < 16; ++r) p[r] = EXP2(sT[r]);

    // P^T rows per lane: t_local = (r&3) + 8*(r>>2) + 4*h (col = sl)
    // target B-frag word w: t-pair (h*8+2w, h*8+2w+1) + m*16
    unsigned int c0, c1, c2, c3, d0, d1, d2, d3;
    asm("v_cvt_pk_bf16_f32 %0, %1, %2" : "=v"(c0) : "v"(p[0]), "v"(p[1]));
    asm("v_cvt_pk_bf16_f32 %0, %1, %2" : "=v"(c1) : "v"(p[2]), "v"(p[3]));
    asm("v_cvt_pk_bf16_f32 %0, %1, %2" : "=v"(c2) : "v"(p[4]), "v"(p[5]));
    asm("v_cvt_pk_bf16_f32 %0, %1, %2" : "=v"(c3) : "v"(p[6]), "v"(p[7]));
    asm("v_cvt_pk_bf16_f32 %0, %1, %2" : "=v"(d0) : "v"(p[8]), "v"(p[9]));
    asm("v_cvt_pk_bf16_f32 %0, %1, %2" : "=v"(d1) : "v"(p[10]), "v"(p[11]));
    asm("v_cvt_pk_bf16_f32 %0, %1, %2" : "=v"(d2) : "v"(p[12]), "v"(p[13]));
    asm("v_cvt_pk_bf16_f32 %0, %1, %2" : "=v"(d3) : "v"(p[14]), "v"(p[15]));
    // swap upper32(dst) <-> lower32(src): yields two B-frag words per swap
    asm("v_permlane32_swap_b32 %0, %1" : "+v"(c0), "+v"(c2));
    asm("v_permlane32_swap_b32 %0, %1" : "+v"(c1), "+v"(c3));
    asm("v_permlane32_swap_b32 %0, %1" : "+v"(d0), "+v"(d2));
    asm("v_permlane32_swap_b32 %0, %1" : "+v"(d1), "+v"(d3));
    F pb0; pb0.u[0] = c0; pb0.u[1] = c1; pb0.u[2] = c2; pb0.u[3] = c3;
    F pb1; pb1.u[0] = d0; pb1.u[1] = d1; pb1.u[2] = d2; pb1.u[3] = d3;

    // A-frag = V^T: A[row=d][k=h*8+j] -> row d, 8 consecutive t (b128)
    F fv0, fv1;
    *(uint4*)fv0.u = *(const uint4*)(lds + voff);        // m=0: t_local 0..15
    *(uint4*)fv1.u = *(const uint4*)(lds + voff + 16);   // m=1: t_local 16..31
    acc = __builtin_amdgcn_mfma_f32_32x32x16_bf16(fv0.v, pb0.v, acc, 0, 0, 0);
    acc = __builtin_amdgcn_mfma_f32_32x32x16_bf16(fv1.v, pb1.v, acc, 0, 0, 0);

    koff += kinc;
    voff += vinc;
  }

  // O^T: col = sl = s, rows d=0..3 in regs 0..3 of lane-half 0; acc[3] = sum_exp
  if (h == 0) {
    const float rl = 1.0f / acc[3];
    ctxb[(size_t)nh * SS + s0 + sl] =
        make_float4(acc[0] * rl, acc[1] * rl, acc[2] * rl, 0.f);
  }
}

// ============================================================
// K3: ctx -> out_proj -> +seq residual -> LN1 -> FF -> LN2 -> linear
// thread idx = n*2304 + s (coalesced ctxb reads / proj writes)
// ============================================================
__global__ __launch_bounds__(256) void k3_mlp(
    const float4* __restrict__ ctxb, const float* __restrict__ x,
    const float* __restrict__ ce, const float* __restrict__ pe,
    const float* __restrict__ opw, const float* __restrict__ opb,
    const float* __restrict__ ln1w, const float* __restrict__ ln1b,
    const float* __restrict__ f1w, const float* __restrict__ f1b,
    const float* __restrict__ f2w, const float* __restrict__ f2b,
    const float* __restrict__ ln2w, const float* __restrict__ ln2b,
    const float* __restrict__ linw, const float* __restrict__ linb,
    float* __restrict__ proj) {
  __shared__ float L[828];
  const int tid = threadIdx.x;
  for (int i = tid; i < 144; i += 256) L[i] = opw[i];
  for (int i = tid; i < 288; i += 256) {
    L[180 + i] = f1w[i];
    L[492 + i] = f2w[i];
  }
  if (tid < 12) {
    L[144 + tid] = opb[tid];
    L[156 + tid] = ln1w[tid];
    L[168 + tid] = ln1b[tid];
    L[780 + tid] = f2b[tid];
    L[792 + tid] = ln2w[tid];
    L[804 + tid] = ln2b[tid];
    L[816 + tid] = linw[tid];
  }
  if (tid < 24) L[468 + tid] = f1b[tid];
  __syncthreads();

  const int idx = blockIdx.x * 256 + tid;  // n*2304 + s
  const int n = idx / 2304;
  const int s = idx % 2304;
  const int p = s % 9;
  const int c = (s / 9) % 64;
  const int b = s / 576;
  const int pi = p / 3, pj = p % 3;
  const int hi = n / 3, wj = n % 3;
  const float val = x[((b * 64 + c) * 5 + (pi + hi)) * 5 + (pj + wj)];

  float ctx[12];
#pragma unroll
  for (int h = 0; h < 4; ++h) {
    const float4 cv = ctxb[(size_t)(n * 4 + h) * SS + s];
    ctx[h * 3 + 0] = cv.x;
    ctx[h * 3 + 1] = cv.y;
    ctx[h * 3 + 2] = cv.z;
  }

  float x1[12];
#pragma unroll
  for (int e = 0; e < 12; ++e) {
    float acc = L[144 + e];
#pragma unroll
    for (int j = 0; j < 12; ++j) acc = fmaf(L[e * 12 + j], ctx[j], acc);
    const float seq_e = ce[c * 12 + e] + pe[n * 12 + e] + val;
    x1[e] = seq_e + acc;
  }

  float mu = 0.f;
#pragma unroll
  for (int e = 0; e < 12; ++e) mu += x1[e];
  mu *= (1.0f / 12.0f);
  float var = 0.f;
#pragma unroll
  for (int e = 0; e < 12; ++e) { const float d = x1[e] - mu; var = fmaf(d, d, var); }
  var *= (1.0f / 12.0f);
  float rs = rsqrtf(var + 1e-5f);
  float h1[12];
#pragma unroll
  for (int e = 0; e < 12; ++e) h1[e] = (x1[e] - mu) * rs * L[156 + e] + L[168 + e];

  float f[24];
#pragma unroll
  for (int r = 0; r < 24; ++r) {
    float acc = L[468 + r];
#pragma unroll
    for (int e = 0; e < 12; ++e) acc = fmaf(L[180 + r * 12 + e], h1[e], acc);
    f[r] = fmaxf(acc, 0.f);
  }
  float x2[12];
#pragma unroll
  for (int e = 0; e < 12; ++e) {
    float acc = L[780 + e];
#pragma unroll
    for (int r = 0; r < 24; ++r) acc = fmaf(L[492 + e * 24 + r], f[r], acc);
    x2[e] = h1[e] + acc;
  }

  mu = 0.f;
#pragma unroll
  for (int e = 0; e < 12; ++e) mu += x2[e];
  mu *= (1.0f / 12.0f);
  var = 0.f;
#pragma unroll
  for (int e = 0; e < 12; ++e) { const float d = x2[e] - mu; var = fmaf(d, d, var); }
  var *= (1.0f / 12.0f);
  rs = rsqrtf(var + 1e-5f);

  float pv = linb[0];
#pragma unroll
  for (int e = 0; e < 12; ++e) {
    const float h2v = (x2[e] - mu) * rs * L[792 + e] + L[804 + e];
    pv = fmaf(L[816 + e], h2v, pv);
  }
  proj[idx] = pv;  // layout [n][s]
}

// ============================================================
// K4: fold (overlap-add); proj layout [n][s]
// ============================================================
__global__ __launch_bounds__(256) void k4_fold(const float* __restrict__ proj,
                                               float* __restrict__ out) {
  const int o = blockIdx.x * 256 + threadIdx.x;
  const int ww = o % 5;
  const int hh = (o / 5) % 5;
  const int c = (o / 25) % 64;
  const int b = o / 1600;
  float sum = 0.f;
#pragma unroll
  for (int i = 0; i < 3; ++i) {
    const int hi = hh - i;
    if (hi < 0 || hi > 2) continue;
#pragma unroll
    for (int j = 0; j < 3; ++j) {
      const int wj = ww - j;
      if (wj < 0 || wj > 2) continue;
      sum += proj[(size_t)(hi * 3 + wj) * 2304 + b * 576 + c * 9 + i * 3 + j];
    }
  }
  out[o] = sum;
}

extern "C" void kernel_launch(void* const* d_in, const int* in_sizes, int n_in,
                              void* d_out, int out_size, void* d_ws, size_t ws_size,
                              hipStream_t stream) {
  const float* x    = (const float*)d_in[0];
  const float* ce   = (const float*)d_in[1];
  const float* pe   = (const float*)d_in[2];
  const float* ipw  = (const float*)d_in[3];
  const float* ipb  = (const float*)d_in[4];
  const float* opw  = (const float*)d_in[5];
  const float* opb  = (const float*)d_in[6];
  const float* ln1w = (const float*)d_in[7];
  const float* ln1b = (const float*)d_in[8];
  const float* f1w  = (const float*)d_in[9];
  const float* f1b  = (const float*)d_in[10];
  const float* f2w  = (const float*)d_in[11];
  const float* f2b  = (const float*)d_in[12];
  const float* ln2w = (const float*)d_in[13];
  const float* ln2b = (const float*)d_in[14];
  const float* linw = (const float*)d_in[15];
  const float* linb = (const float*)d_in[16];

  // ws layout (bytes):
  //   Qb   [0,        663552)   36*2304*4 bf16
  //   Kb   [663552,   1327104)
  //   Vt   [1327104,  1990656)  36*4*2304 bf16
  //   ctxb [1990656,  3317760)  36*2304 float4
  //   proj [3317760,  3400704)  9*2304 f32
  unsigned short* Qb = (unsigned short*)d_ws;
  unsigned short* Kb = Qb + 331776;
  unsigned short* Vt = Kb + 331776;
  float4* ctxb = (float4*)((char*)d_ws + 1990656);
  float* proj = (float*)((char*)d_ws + 3317760);

  k1_embed_qkv<<<81, 256, 0, stream>>>(x, ce, pe, ipw, ipb, Qb, Kb, Vt);
  k2_attn<<<648, 256, 0, stream>>>(Qb, Kb, Vt, ctxb);
  k3_mlp<<<81, 256, 0, stream>>>(ctxb, x, ce, pe, opw, opb, ln1w, ln1b, f1w,
                                 f1b, f2w, f2b, ln2w, ln2b, linw, linb, proj);
  k4_fold<<<25, 256, 0, stream>>>(proj, (float*)d_out);
}

// Round 4
// 52.547 us; speedup vs baseline: 1.5732x; 1.0448x over previous
//
#include <hip/hip_runtime.h>
#include <hip/hip_bf16.h>
#include <math.h>

// ---- problem constants ----
#define SS 2304       // S = B*C*K*K
#define QSCALE 0.8329506128860126f  // log2(e)/sqrt(3)
#define TSPLIT 4
#define TCH 576       // SS / TSPLIT

#if defined(__has_builtin)
#if __has_builtin(__builtin_amdgcn_exp2f)
#define EXP2(x) __builtin_amdgcn_exp2f(x)
#endif
#endif
#ifndef EXP2
#define EXP2(x) exp2f(x)
#endif

typedef short s8v __attribute__((ext_vector_type(8)));
typedef float f32x16 __attribute__((ext_vector_type(16)));

static __device__ __forceinline__ unsigned short f2b(float f) {
  __hip_bfloat16 h = __float2bfloat16(f);
  return __builtin_bit_cast(unsigned short, h);
}

// ============================================================
// K1: seq = ce[c]+pe[n]+x_val; one of {q,k,v} 12-row GEMV per thread.
// grid = 243 blocks: grp = bid/81 (uniform per block), idx = (bid%81)*256+tid
// layouts: Qb[nh][s][4] (scaled, pad0) | Kb[nh][t][4] | Vt[nh*4+d][t], d=3 ones
// ============================================================
__global__ __launch_bounds__(256) void k1_embed_qkv(
    const float* __restrict__ x, const float* __restrict__ ce,
    const float* __restrict__ pe, const float* __restrict__ w,
    const float* __restrict__ bias, unsigned short* __restrict__ Qb,
    unsigned short* __restrict__ Kb, unsigned short* __restrict__ Vt) {
  __shared__ float lw[144];
  __shared__ float lb[12];
  const int tid = threadIdx.x;
  const int grp = blockIdx.x / 81;       // 0=q 1=k 2=v
  const int ib = blockIdx.x % 81;
  for (int i = tid; i < 144; i += 256) lw[i] = w[grp * 144 + i];
  if (tid < 12) lb[tid] = bias[grp * 12 + tid];
  __syncthreads();

  const int idx = ib * 256 + tid;        // n*2304 + s
  const int n = idx / 2304;
  const int s = idx % 2304;
  const int p = s % 9;
  const int c = (s / 9) % 64;
  const int b = s / 576;
  const int pi = p / 3, pj = p % 3;
  const int hi = n / 3, wj = n % 3;
  const float val = x[((b * 64 + c) * 5 + (pi + hi)) * 5 + (pj + wj)];

  float sq[12];
#pragma unroll
  for (int e = 0; e < 12; ++e) sq[e] = ce[c * 12 + e] + pe[n * 12 + e] + val;

  float out[12];
#pragma unroll
  for (int r = 0; r < 12; ++r) {
    float acc = lb[r];
#pragma unroll
    for (int e = 0; e < 12; ++e) acc = fmaf(lw[r * 12 + e], sq[e], acc);
    out[r] = acc;
  }

  if (grp == 0) {
#pragma unroll
    for (int h = 0; h < 4; ++h) {
      ushort4 qq;
      qq.x = f2b(out[h * 3 + 0] * QSCALE);
      qq.y = f2b(out[h * 3 + 1] * QSCALE);
      qq.z = f2b(out[h * 3 + 2] * QSCALE);
      qq.w = 0;
      *(ushort4*)(Qb + ((size_t)(n * 4 + h) * SS + s) * 4) = qq;
    }
  } else if (grp == 1) {
#pragma unroll
    for (int h = 0; h < 4; ++h) {
      ushort4 kk;
      kk.x = f2b(out[h * 3 + 0]);
      kk.y = f2b(out[h * 3 + 1]);
      kk.z = f2b(out[h * 3 + 2]);
      kk.w = 0;
      *(ushort4*)(Kb + ((size_t)(n * 4 + h) * SS + s) * 4) = kk;
    }
  } else {
#pragma unroll
    for (int h = 0; h < 4; ++h) {
      const size_t vb = (size_t)((n * 4 + h) * 4) * SS + s;
      Vt[vb + 0 * SS] = f2b(out[h * 3 + 0]);
      Vt[vb + 1 * SS] = f2b(out[h * 3 + 1]);
      Vt[vb + 2 * SS] = f2b(out[h * 3 + 2]);
      Vt[vb + 3 * SS] = 0x3F80;  // ones row -> sum_exp rides in acc[3]
    }
  }
}

// ============================================================
// K2: MFMA flash attention, t-split partials (unnormalized).
// block = (nh, schunk of 128 s, tc of 576 t); 36*18*4 = 2592 blocks.
// LDS (ushort idx): K [0,2304) | V^T rows base 2304 stride 584 | zero pad 4640
// part[(nh*TSPLIT+tc)*SS + s] = float4(o0,o1,o2,sum_exp)  (unnormalized)
// staging: K tile = 576 tok * 4 ushort = 288 uint4; V = 4 rows * 72 uint4
// ============================================================
__global__ __launch_bounds__(256) void k2_attn(
    const unsigned short* __restrict__ Qb, const unsigned short* __restrict__ Kb,
    const unsigned short* __restrict__ Vt, float4* __restrict__ part) {
  __shared__ unsigned short lds[4672];
  const int tid = threadIdx.x;
  const int tc = blockIdx.x & 3;
  const int schunk = (blockIdx.x >> 2) % 18;
  const int nh = blockIdx.x / 72;
  const int t0 = tc * TCH;

  {
    const uint4* sk = (const uint4*)(Kb + ((size_t)nh * SS + t0) * 4);
    for (int i = tid; i < 288; i += 256) ((uint4*)lds)[i] = sk[i];
    for (int i = tid; i < 288; i += 256) {
      const int r = i / 72, cc = i - r * 72;   // 72 uint4 per 576-ushort row
      *(uint4*)(lds + 2304 + r * 584 + cc * 8) =
          *(const uint4*)(Vt + (size_t)(nh * 4 + r) * SS + t0 + cc * 8);
    }
    if (tid < 4) *(uint4*)(lds + 4640 + tid * 8) = make_uint4(0, 0, 0, 0);
  }
  __syncthreads();

  const int lane = tid & 63;
  const int wv = tid >> 6;
  const int h = lane >> 5;
  const int sl = lane & 31;
  const int s0 = (schunk * 4 + wv) * 32;

  union F { s8v v; unsigned int u[4]; };

  F fq;
  {
    const uint2 qw = *(const uint2*)(Qb + ((size_t)nh * SS + s0 + sl) * 4);
    fq.u[0] = h ? 0u : qw.x;
    fq.u[1] = h ? 0u : qw.y;
    fq.u[2] = 0u;
    fq.u[3] = 0u;
  }

  int koff = h ? 4640 : sl * 4;
  const int kinc = h ? 0 : 128;          // 32 tokens * 4 ushorts
  int voff = (sl < 4) ? (2304 + sl * 584 + h * 8) : 4640;
  const int vinc = (sl < 4) ? 32 : 0;

  const f32x16 kz = {};
  f32x16 acc = {};
#pragma unroll 2
  for (int t = 0; t < TCH / 32; ++t) {
    F fa;
    const uint2 kw = *(const uint2*)(lds + koff);
    fa.u[0] = kw.x; fa.u[1] = kw.y; fa.u[2] = 0u; fa.u[3] = 0u;
    f32x16 sT = __builtin_amdgcn_mfma_f32_32x32x16_bf16(fa.v, fq.v, kz, 0, 0, 0);

    unsigned int c0, c1, c2, c3, d0, d1, d2, d3;
    {
      const float p0 = EXP2(sT[0]), p1 = EXP2(sT[1]), p2 = EXP2(sT[2]),
                  p3 = EXP2(sT[3]), p4 = EXP2(sT[4]), p5 = EXP2(sT[5]),
                  p6 = EXP2(sT[6]), p7 = EXP2(sT[7]);
      asm("v_cvt_pk_bf16_f32 %0, %1, %2" : "=v"(c0) : "v"(p0), "v"(p1));
      asm("v_cvt_pk_bf16_f32 %0, %1, %2" : "=v"(c1) : "v"(p2), "v"(p3));
      asm("v_cvt_pk_bf16_f32 %0, %1, %2" : "=v"(c2) : "v"(p4), "v"(p5));
      asm("v_cvt_pk_bf16_f32 %0, %1, %2" : "=v"(c3) : "v"(p6), "v"(p7));
    }
    {
      const float p8 = EXP2(sT[8]), p9 = EXP2(sT[9]), pa = EXP2(sT[10]),
                  pb = EXP2(sT[11]), pc = EXP2(sT[12]), pd = EXP2(sT[13]),
                  pe = EXP2(sT[14]), pf = EXP2(sT[15]);
      asm("v_cvt_pk_bf16_f32 %0, %1, %2" : "=v"(d0) : "v"(p8), "v"(p9));
      asm("v_cvt_pk_bf16_f32 %0, %1, %2" : "=v"(d1) : "v"(pa), "v"(pb));
      asm("v_cvt_pk_bf16_f32 %0, %1, %2" : "=v"(d2) : "v"(pc), "v"(pd));
      asm("v_cvt_pk_bf16_f32 %0, %1, %2" : "=v"(d3) : "v"(pe), "v"(pf));
    }
    asm("v_permlane32_swap_b32 %0, %1" : "+v"(c0), "+v"(c2));
    asm("v_permlane32_swap_b32 %0, %1" : "+v"(c1), "+v"(c3));
    asm("v_permlane32_swap_b32 %0, %1" : "+v"(d0), "+v"(d2));
    asm("v_permlane32_swap_b32 %0, %1" : "+v"(d1), "+v"(d3));
    F pb0; pb0.u[0] = c0; pb0.u[1] = c1; pb0.u[2] = c2; pb0.u[3] = c3;
    F pb1; pb1.u[0] = d0; pb1.u[1] = d1; pb1.u[2] = d2; pb1.u[3] = d3;

    F fv0, fv1;
    *(uint4*)fv0.u = *(const uint4*)(lds + voff);
    *(uint4*)fv1.u = *(const uint4*)(lds + voff + 16);
    acc = __builtin_amdgcn_mfma_f32_32x32x16_bf16(fv0.v, pb0.v, acc, 0, 0, 0);
    acc = __builtin_amdgcn_mfma_f32_32x32x16_bf16(fv1.v, pb1.v, acc, 0, 0, 0);

    koff += kinc;
    voff += vinc;
  }

  if (h == 0) {
    part[((size_t)(nh * TSPLIT + tc)) * SS + s0 + sl] =
        make_float4(acc[0], acc[1], acc[2], acc[3]);
  }
}

// ============================================================
// K3: combine partials -> ctx; out_proj; +seq; LN1; FF; LN2; linear; FOLD.
// block = one (b,c) pair: 81 tokens (p,n), 128 threads; 256 blocks.
// ============================================================
__global__ __launch_bounds__(128) void k3_mlp_fold(
    const float4* __restrict__ part, const float* __restrict__ x,
    const float* __restrict__ ce, const float* __restrict__ pe,
    const float* __restrict__ opw, const float* __restrict__ opb,
    const float* __restrict__ ln1w, const float* __restrict__ ln1b,
    const float* __restrict__ f1w, const float* __restrict__ f1b,
    const float* __restrict__ f2w, const float* __restrict__ f2b,
    const float* __restrict__ ln2w, const float* __restrict__ ln2b,
    const float* __restrict__ linw, const float* __restrict__ linb,
    float* __restrict__ out) {
  __shared__ float L[828];
  __shared__ float pvs[81];
  const int tid = threadIdx.x;
  for (int i = tid; i < 144; i += 128) L[i] = opw[i];
  for (int i = tid; i < 288; i += 128) {
    L[180 + i] = f1w[i];
    L[492 + i] = f2w[i];
  }
  if (tid < 12) {
    L[144 + tid] = opb[tid];
    L[156 + tid] = ln1w[tid];
    L[168 + tid] = ln1b[tid];
    L[780 + tid] = f2b[tid];
    L[792 + tid] = ln2w[tid];
    L[804 + tid] = ln2b[tid];
    L[816 + tid] = linw[tid];
  }
  if (tid < 24) L[468 + tid] = f1b[tid];
  __syncthreads();

  const int bc = blockIdx.x;             // b*64 + c
  const int c = bc & 63;

  if (tid < 81) {
    const int n = tid / 9;
    const int p = tid % 9;
    const int s = bc * 9 + p;
    const int pi = p / 3, pj = p % 3;
    const int hi = n / 3, wj = n % 3;
    const float val = x[(bc * 5 + (pi + hi)) * 5 + (pj + wj)];

    float ctx[12];
#pragma unroll
    for (int h = 0; h < 4; ++h) {
      const float4* pp = part + ((size_t)((n * 4 + h) * TSPLIT)) * SS + s;
      float l = 0.f, a0 = 0.f, a1 = 0.f, a2 = 0.f;
#pragma unroll
      for (int t = 0; t < TSPLIT; ++t) {
        const float4 v = pp[(size_t)t * SS];
        a0 += v.x; a1 += v.y; a2 += v.z; l += v.w;
      }
      const float rl = 1.0f / l;
      ctx[h * 3 + 0] = a0 * rl;
      ctx[h * 3 + 1] = a1 * rl;
      ctx[h * 3 + 2] = a2 * rl;
    }

    float x1[12];
#pragma unroll
    for (int e = 0; e < 12; ++e) {
      float acc = L[144 + e];
#pragma unroll
      for (int j = 0; j < 12; ++j) acc = fmaf(L[e * 12 + j], ctx[j], acc);
      const float seq_e = ce[c * 12 + e] + pe[n * 12 + e] + val;
      x1[e] = seq_e + acc;
    }

    float mu = 0.f;
#pragma unroll
    for (int e = 0; e < 12; ++e) mu += x1[e];
    mu *= (1.0f / 12.0f);
    float var = 0.f;
#pragma unroll
    for (int e = 0; e < 12; ++e) { const float d = x1[e] - mu; var = fmaf(d, d, var); }
    var *= (1.0f / 12.0f);
    float rs = rsqrtf(var + 1e-5f);
    float h1[12];
#pragma unroll
    for (int e = 0; e < 12; ++e) h1[e] = (x1[e] - mu) * rs * L[156 + e] + L[168 + e];

    float f[24];
#pragma unroll
    for (int r = 0; r < 24; ++r) {
      float acc = L[468 + r];
#pragma unroll
      for (int e = 0; e < 12; ++e) acc = fmaf(L[180 + r * 12 + e], h1[e], acc);
      f[r] = fmaxf(acc, 0.f);
    }
    float x2[12];
#pragma unroll
    for (int e = 0; e < 12; ++e) {
      float acc = L[780 + e];
#pragma unroll
      for (int r = 0; r < 24; ++r) acc = fmaf(L[492 + e * 24 + r], f[r], acc);
      x2[e] = h1[e] + acc;
    }

    mu = 0.f;
#pragma unroll
    for (int e = 0; e < 12; ++e) mu += x2[e];
    mu *= (1.0f / 12.0f);
    var = 0.f;
#pragma unroll
    for (int e = 0; e < 12; ++e) { const float d = x2[e] - mu; var = fmaf(d, d, var); }
    var *= (1.0f / 12.0f);
    rs = rsqrtf(var + 1e-5f);

    float pv = linb[0];
#pragma unroll
    for (int e = 0; e < 12; ++e) {
      const float h2v = (x2[e] - mu) * rs * L[792 + e] + L[804 + e];
      pv = fmaf(L[816 + e], h2v, pv);
    }
    pvs[tid] = pv;                       // pvs[n*9 + p]
  }
  __syncthreads();

  if (tid < 25) {
    const int hh = tid / 5, ww = tid % 5;
    float sum = 0.f;
#pragma unroll
    for (int i = 0; i < 3; ++i) {
      const int hi = hh - i;
      if (hi < 0 || hi > 2) continue;
#pragma unroll
      for (int j = 0; j < 3; ++j) {
        const int wj = ww - j;
        if (wj < 0 || wj > 2) continue;
        sum += pvs[(hi * 3 + wj) * 9 + (i * 3 + j)];
      }
    }
    out[bc * 25 + tid] = sum;
  }
}

extern "C" void kernel_launch(void* const* d_in, const int* in_sizes, int n_in,
                              void* d_out, int out_size, void* d_ws, size_t ws_size,
                              hipStream_t stream) {
  const float* x    = (const float*)d_in[0];
  const float* ce   = (const float*)d_in[1];
  const float* pe   = (const float*)d_in[2];
  const float* ipw  = (const float*)d_in[3];
  const float* ipb  = (const float*)d_in[4];
  const float* opw  = (const float*)d_in[5];
  const float* opb  = (const float*)d_in[6];
  const float* ln1w = (const float*)d_in[7];
  const float* ln1b = (const float*)d_in[8];
  const float* f1w  = (const float*)d_in[9];
  const float* f1b  = (const float*)d_in[10];
  const float* f2w  = (const float*)d_in[11];
  const float* f2b  = (const float*)d_in[12];
  const float* ln2w = (const float*)d_in[13];
  const float* ln2b = (const float*)d_in[14];
  const float* linw = (const float*)d_in[15];
  const float* linb = (const float*)d_in[16];

  // ws layout (bytes):
  //   Qb   [0,        663552)   36*2304*4 bf16
  //   Kb   [663552,   1327104)
  //   Vt   [1327104,  1990656)  36*4*2304 bf16
  //   part [1990656,  7299072)  36*4*2304 float4
  unsigned short* Qb = (unsigned short*)d_ws;
  unsigned short* Kb = Qb + 331776;
  unsigned short* Vt = Kb + 331776;
  float4* part = (float4*)((char*)d_ws + 1990656);

  k1_embed_qkv<<<243, 256, 0, stream>>>(x, ce, pe, ipw, ipb, Qb, Kb, Vt);
  k2_attn<<<36 * 18 * TSPLIT, 256, 0, stream>>>(Qb, Kb, Vt, part);
  k3_mlp_fold<<<256, 128, 0, stream>>>(part, x, ce, pe, opw, opb, ln1w, ln1b,
                                       f1w, f1b, f2w, f2b, ln2w, ln2b, linw,
                                       linb, (float*)d_out);
}